// Round 9
// baseline (210.559 us; speedup 1.0000x reference)
//
#include <hip/hip_runtime.h>
#include <math.h>

// TiSASRec forward on MI355X — round 8:
//  - attn: Qt table fused INTO the attention kernel (computed in LDS from
//    L2-resident tKT, reused 8x per block) — kills the 18.7 MB Qt HBM
//    round-trip that pinned attn at ~50us (time tracked FETCH/500GB/s
//    across R4/R6/R7). Blocks = 8 contiguous queries x 8 waves.
//  - qt_kernel launch removed (8 -> 6 launches). Rest identical to R6/R7.
// B=32, L=200, D=64, H=2, dh=32, NL=2.
#define BB 32
#define LLEN 200
#define DD 64
#define HH 2
#define NLAYER 2
#define BLD (BB * LLEN * DD)
#define TSPAN1 366   // TIME_SPAN+1

__device__ inline float waveSum(float v) {
#pragma unroll
    for (int off = 32; off > 0; off >>= 1) v += __shfl_xor(v, off);
    return v;
}
__device__ inline float halfSum(float v) {
    v += __shfl_xor(v, 1);
    v += __shfl_xor(v, 2);
    v += __shfl_xor(v, 4);
    v += __shfl_xor(v, 8);
    v += __shfl_xor(v, 16);
    return v;
}
__device__ inline float halfMax(float v) {
    v = fmaxf(v, __shfl_xor(v, 1));
    v = fmaxf(v, __shfl_xor(v, 2));
    v = fmaxf(v, __shfl_xor(v, 4));
    v = fmaxf(v, __shfl_xor(v, 8));
    v = fmaxf(v, __shfl_xor(v, 16));
    return v;
}

// grid=11: m<10 -> transpose 64x64 weights; m==10 -> tK_emb^T [64][366]
__global__ void transpose_kernel(const float* __restrict__ Wq,
                                 const float* __restrict__ Wk,
                                 const float* __restrict__ Wv,
                                 const float* __restrict__ W1,
                                 const float* __restrict__ W2,
                                 const float* __restrict__ tK_emb,
                                 float* __restrict__ wt,
                                 float* __restrict__ tKT) {
    int m = blockIdx.x;
    if (m < 10) {
        const float* src;
        switch (m % 5) {
            case 0: src = Wq; break;
            case 1: src = Wk; break;
            case 2: src = Wv; break;
            case 3: src = W1; break;
            default: src = W2; break;
        }
        src += (m / 5) * DD * DD;
        float* dst = wt + m * DD * DD;
        for (int e = threadIdx.x; e < DD * DD; e += 256) {
            int d = e >> 6, j = e & 63;
            dst[j * DD + d] = src[e];
        }
    } else {
        for (int e = threadIdx.x; e < TSPAN1 * DD; e += 256) {
            int t = e >> 6, d = e & 63;
            tKT[d * TSPAN1 + t] = tK_emb[e];
        }
    }
}

// Layer-0 entry: 4 rows/block, wave per row. Embedding gather fused.
__global__ void ln_qkv_kernel(const int* __restrict__ log_ids,
                              const float* __restrict__ item_emb,
                              const float* __restrict__ g,
                              const float* __restrict__ bln,
                              const float* __restrict__ WqT, const float* __restrict__ bq,
                              const float* __restrict__ WkT, const float* __restrict__ bk,
                              const float* __restrict__ WvT, const float* __restrict__ bv,
                              const float* __restrict__ posK,
                              const float* __restrict__ posV,
                              float* __restrict__ q,
                              float* __restrict__ Q, float* __restrict__ K,
                              float* __restrict__ V) {
    __shared__ float qs[4][DD], xs[4][DD];
    int tid = threadIdx.x;
    int wid = tid >> 6, d = tid & 63;
    int row = blockIdx.x * 4 + wid;
    int l = row % LLEN;
    int id = log_ids[row];
    float xv = (id == 0) ? 0.0f : item_emb[id * DD + d] * 8.0f;  // sqrt(64)*keep
    xs[wid][d] = xv;
    float m = waveSum(xv) * (1.0f / 64.0f);
    float c = xv - m;
    float var = waveSum(c * c) * (1.0f / 64.0f);
    float qv = (c / sqrtf(var + 1e-8f)) * g[d] + bln[d];
    qs[wid][d] = qv;
    q[row * DD + d] = qv;
    float aq = bq[d], ak = bk[d], av = bv[d];
#pragma unroll 8
    for (int j = 0; j < DD; ++j) {
        aq = fmaf(qs[wid][j], WqT[j * DD + d], aq);
        ak = fmaf(xs[wid][j], WkT[j * DD + d], ak);
        av = fmaf(xs[wid][j], WvT[j * DD + d], av);
    }
    Q[row * DD + d] = aq;
    K[row * DD + d] = ak + posK[l * DD + d];
    V[row * DD + d] = av + posV[l * DD + d];
}

// Attention with fused qt: block = 8 contiguous queries (8 waves, 512 thr).
// Cooperative phase: qt_s[qq][h*366+t] = Qh[qq] . tK[t]h from L2-resident
// tKT (each load reused 8x). Then per-wave: buckets, 4-key-group scores,
// softmax, PV — R6 structure. grid = B*25.
__global__ void __launch_bounds__(512, 6)
attn_kernel(const float* __restrict__ Q,
            const float* __restrict__ Keff,
            const float* __restrict__ Veff,
            const int* __restrict__ log_times,
            const float* __restrict__ tKT,
            const float* __restrict__ tV_emb,
            float* __restrict__ out) {
    __shared__ int t_s[LLEN];
    __shared__ float Qs[8][DD];
    __shared__ float qt_s[8][2 * TSPAN1];
    __shared__ float sc[8][HH][LLEN];
    __shared__ unsigned short tm_s[8][LLEN];

    int tid = threadIdx.x;
    int w = tid >> 6;            // wave = block-local query 0..7
    int lane = tid & 63;
    int bi = blockIdx.x / 25;
    int t8 = blockIdx.x % 25;
    int qi = t8 * 8 + w;
    int row = bi * LLEN + qi;
    int len = qi + 1;

    if (tid < LLEN) t_s[tid] = log_times[bi * LLEN + tid];
    Qs[w][lane] = Q[row * DD + lane];
    __syncthreads();

    // per-wave bucket table (own region — same-wave read, no barrier needed)
    int tq = t_s[qi];
    for (int k = lane; k < len; k += 64) {
        int dt = tq - t_s[k];
        if (dt < 0) dt = -dt;
        tm_s[w][k] = (unsigned short)(int)fminf((float)dt * (1.0f / 86400.0f), 365.0f);
    }

    // cooperative qt: unit u = chunk*2+h, 12 units over 8 waves
    for (int u = w; u < 12; u += 8) {
        int chunk = u >> 1, h = u & 1;
        int tt = chunk * 64 + lane;
        if (tt < TSPAN1) {
            float a0 = 0, a1 = 0, a2 = 0, a3 = 0, a4 = 0, a5 = 0, a6 = 0, a7 = 0;
            const float* tk = tKT + (h * 32) * TSPAN1 + tt;
            const float* qsh = &Qs[0][h * 32];
            for (int d = 0; d < 32; ++d) {
                float v = tk[d * TSPAN1];            // coalesced, L2-hot
                a0 = fmaf(v, qsh[0 * DD + d], a0);   // LDS broadcasts
                a1 = fmaf(v, qsh[1 * DD + d], a1);
                a2 = fmaf(v, qsh[2 * DD + d], a2);
                a3 = fmaf(v, qsh[3 * DD + d], a3);
                a4 = fmaf(v, qsh[4 * DD + d], a4);
                a5 = fmaf(v, qsh[5 * DD + d], a5);
                a6 = fmaf(v, qsh[6 * DD + d], a6);
                a7 = fmaf(v, qsh[7 * DD + d], a7);
            }
            int o = h * TSPAN1 + tt;
            qt_s[0][o] = a0; qt_s[1][o] = a1; qt_s[2][o] = a2; qt_s[3][o] = a3;
            qt_s[4][o] = a4; qt_s[5][o] = a5; qt_s[6][o] = a6; qt_s[7][o] = a7;
        }
    }
    __syncthreads();

    int h = lane >> 5;       // head
    int l5 = lane & 31;
    int cch = l5 >> 2;       // channel chunk 0..7
    int jo = l5 & 3;         // key offset in group
    float4 qv = ((const float4*)(&Qs[w][0]))[h * 8 + cch];
    const float4* K4 = (const float4*)(Keff + bi * LLEN * DD);
    const float* qtrow = &qt_s[w][h * TSPAN1];
    const float scale = 0.17677669529663687f;  // 1/sqrt(32)

    // phase 1: scores, 4 keys per iteration
    for (int k0 = 0; k0 < len; k0 += 4) {
        int k = k0 + jo;
        int kc = (k < len) ? k : (len - 1);
        int bucket = tm_s[w][kc];
        float4 kv = K4[kc * 16 + h * 8 + cch];
        float p = qv.x * kv.x + qv.y * kv.y + qv.z * kv.z + qv.w * kv.w;
        p += __shfl_xor(p, 4);
        p += __shfl_xor(p, 8);
        p += __shfl_xor(p, 16);   // full 32-dot for (h, key k)
        float s = (p + qtrow[bucket]) * scale;
        if (cch == 0 && k < len) sc[w][h][k] = s;
    }

    // phase 2: softmax (lanes 0..31 head 0, 32..63 head 1; same wave)
    {
        float m = -INFINITY;
        for (int k = l5; k < len; k += 32) m = fmaxf(m, sc[w][h][k]);
        m = halfMax(m);
        float s = 0.0f;
        for (int k = l5; k < len; k += 32) {
            float e = expf(sc[w][h][k] - m);
            sc[w][h][k] = e;
            s += e;
        }
        s = halfSum(s);
        float inv = 1.0f / s;
        for (int k = l5; k < len; k += 32) sc[w][h][k] *= inv;
    }

    // phase 3: out[d] = sum_k A[h][k] * (V_eff[k][d] + tV[bucket[k]][d])
    const float* Vb = Veff + bi * LLEN * DD + lane;
    const float* tVl = tV_emb + lane;
    float acc0 = 0.0f, acc1 = 0.0f, acc2 = 0.0f, acc3 = 0.0f;
    int k = 0;
    for (; k + 4 <= len; k += 4) {
        int b0 = tm_s[w][k + 0];
        int b1 = tm_s[w][k + 1];
        int b2 = tm_s[w][k + 2];
        int b3 = tm_s[w][k + 3];
        float a0 = sc[w][h][k + 0];
        float a1 = sc[w][h][k + 1];
        float a2 = sc[w][h][k + 2];
        float a3 = sc[w][h][k + 3];
        acc0 = fmaf(a0, Vb[(k + 0) * DD] + tVl[b0 * DD], acc0);
        acc1 = fmaf(a1, Vb[(k + 1) * DD] + tVl[b1 * DD], acc1);
        acc2 = fmaf(a2, Vb[(k + 2) * DD] + tVl[b2 * DD], acc2);
        acc3 = fmaf(a3, Vb[(k + 3) * DD] + tVl[b3 * DD], acc3);
    }
    for (; k < len; ++k) {
        int b0 = tm_s[w][k];
        acc0 = fmaf(sc[w][h][k], Vb[k * DD] + tVl[b0 * DD], acc0);
    }
    out[row * DD + lane] = (acc0 + acc1) + (acc2 + acc3);
}

// MID: addln_ffn(layer i) fused with ln_qkv(layer i+1). 4 rows/block.
__global__ void mid_kernel(const float* __restrict__ qin,
                           const float* __restrict__ att,
                           const float* __restrict__ g2, const float* __restrict__ b2ln,
                           const float* __restrict__ W1T, const float* __restrict__ b1v,
                           const float* __restrict__ W2T, const float* __restrict__ b2v,
                           const int* __restrict__ log_ids,
                           const float* __restrict__ g1n, const float* __restrict__ b1n,
                           const float* __restrict__ WqT, const float* __restrict__ bq,
                           const float* __restrict__ WkT, const float* __restrict__ bk,
                           const float* __restrict__ WvT, const float* __restrict__ bv,
                           const float* __restrict__ posK,
                           const float* __restrict__ posV,
                           float* __restrict__ q,
                           float* __restrict__ Q, float* __restrict__ K,
                           float* __restrict__ V) {
    __shared__ float xs[4][DD], hs[4][DD], qs[4][DD];
    int tid = threadIdx.x;
    int wid = tid >> 6, d = tid & 63;
    int row = blockIdx.x * 4 + wid;
    int l = row % LLEN;
    // --- addln + FFN ---
    float v = qin[row * DD + d] + att[row * DD + d];
    float m = waveSum(v) * (1.0f / 64.0f);
    float c = v - m;
    float var = waveSum(c * c) * (1.0f / 64.0f);
    float xv = (c / sqrtf(var + 1e-8f)) * g2[d] + b2ln[d];
    xs[wid][d] = xv;
    float a = b1v[d];
#pragma unroll 8
    for (int j = 0; j < DD; ++j) a = fmaf(xs[wid][j], W1T[j * DD + d], a);
    hs[wid][d] = fmaxf(a, 0.0f);
    float o = b2v[d];
#pragma unroll 8
    for (int j = 0; j < DD; ++j) o = fmaf(hs[wid][j], W2T[j * DD + d], o);
    float res = xv + o;
    if (log_ids[row] == 0) res = 0.0f;
    // --- next layer: LN1 + QKV projection ---
    float m2 = waveSum(res) * (1.0f / 64.0f);
    float c2 = res - m2;
    float var2 = waveSum(c2 * c2) * (1.0f / 64.0f);
    float qv = (c2 / sqrtf(var2 + 1e-8f)) * g1n[d] + b1n[d];
    qs[wid][d] = qv;
    xs[wid][d] = res;
    q[row * DD + d] = qv;
    float aq = bq[d], ak = bk[d], av = bv[d];
#pragma unroll 8
    for (int j = 0; j < DD; ++j) {
        aq = fmaf(qs[wid][j], WqT[j * DD + d], aq);
        ak = fmaf(xs[wid][j], WkT[j * DD + d], ak);
        av = fmaf(xs[wid][j], WvT[j * DD + d], av);
    }
    Q[row * DD + d] = aq;
    K[row * DD + d] = ak + posK[l * DD + d];
    V[row * DD + d] = av + posV[l * DD + d];
}

// END: addln_ffn(last layer) fused with final LN + logits. 4 rows/block.
__global__ void end_kernel(const float* __restrict__ qin,
                           const float* __restrict__ att,
                           const float* __restrict__ g2, const float* __restrict__ b2ln,
                           const float* __restrict__ W1T, const float* __restrict__ b1v,
                           const float* __restrict__ W2T, const float* __restrict__ b2v,
                           const int* __restrict__ log_ids,
                           const float* __restrict__ lnf_g, const float* __restrict__ lnf_b,
                           const float* __restrict__ item_emb,
                           const int* __restrict__ pos_ids,
                           const int* __restrict__ neg_ids,
                           float* __restrict__ out) {
    __shared__ float xs[4][DD], hs[4][DD];
    int tid = threadIdx.x;
    int wid = tid >> 6, d = tid & 63;
    int row = blockIdx.x * 4 + wid;
    float v = qin[row * DD + d] + att[row * DD + d];
    float m = waveSum(v) * (1.0f / 64.0f);
    float c = v - m;
    float var = waveSum(c * c) * (1.0f / 64.0f);
    float xv = (c / sqrtf(var + 1e-8f)) * g2[d] + b2ln[d];
    xs[wid][d] = xv;
    float a = b1v[d];
#pragma unroll 8
    for (int j = 0; j < DD; ++j) a = fmaf(xs[wid][j], W1T[j * DD + d], a);
    hs[wid][d] = fmaxf(a, 0.0f);
    float o = b2v[d];
#pragma unroll 8
    for (int j = 0; j < DD; ++j) o = fmaf(hs[wid][j], W2T[j * DD + d], o);
    float res = xv + o;
    if (log_ids[row] == 0) res = 0.0f;
    // --- final LN + logits ---
    float m2 = waveSum(res) * (1.0f / 64.0f);
    float c2 = res - m2;
    float var2 = waveSum(c2 * c2) * (1.0f / 64.0f);
    float f = (c2 / sqrtf(var2 + 1e-8f)) * lnf_g[d] + lnf_b[d];
    int pid = pos_ids[row];
    int nid = neg_ids[row];
    float p = waveSum(f * item_emb[pid * DD + d]);
    float n = waveSum(f * item_emb[nid * DD + d]);
    if (d == 0) {
        out[row] = p;
        out[BB * LLEN + row] = n;
    }
}

extern "C" void kernel_launch(void* const* d_in, const int* in_sizes, int n_in,
                              void* d_out, int out_size, void* d_ws, size_t ws_size,
                              hipStream_t stream) {
    const int* log_ids = (const int*)d_in[0];
    const int* log_times = (const int*)d_in[1];
    const int* pos_ids = (const int*)d_in[2];
    const int* neg_ids = (const int*)d_in[3];
    const float* item_emb = (const float*)d_in[4];
    const float* posK = (const float*)d_in[5];
    const float* posV = (const float*)d_in[6];
    const float* tK_emb = (const float*)d_in[7];
    const float* tV_emb = (const float*)d_in[8];
    const float* ln1_g = (const float*)d_in[9];
    const float* ln1_b = (const float*)d_in[10];
    const float* Wq = (const float*)d_in[11];
    const float* bq = (const float*)d_in[12];
    const float* Wk = (const float*)d_in[13];
    const float* bk = (const float*)d_in[14];
    const float* Wv = (const float*)d_in[15];
    const float* bv = (const float*)d_in[16];
    const float* ln2_g = (const float*)d_in[17];
    const float* ln2_b = (const float*)d_in[18];
    const float* W1 = (const float*)d_in[19];
    const float* b1 = (const float*)d_in[20];
    const float* W2 = (const float*)d_in[21];
    const float* b2 = (const float*)d_in[22];
    const float* lnf_g = (const float*)d_in[23];
    const float* lnf_b = (const float*)d_in[24];

    float* ws = (float*)d_ws;
    float* q = ws;                        // ln1 output (residual)
    float* Qb = q + BLD;
    float* Kb = Qb + BLD;
    float* Vb = Kb + BLD;
    float* att = Vb + BLD;
    float* wt = att + BLD;                // 10 x 64x64 transposed weights
    float* tKT = wt + 10 * DD * DD;       // [64][366]

    const int nrow = BB * LLEN;           // 6400

    const float* W1T0 = wt + 3 * DD * DD;
    const float* W2T0 = wt + 4 * DD * DD;
    const float* W1T1 = wt + 8 * DD * DD;
    const float* W2T1 = wt + 9 * DD * DD;

    transpose_kernel<<<11, 256, 0, stream>>>(Wq, Wk, Wv, W1, W2, tK_emb, wt, tKT);

    // layer 0 entry (embed fused)
    ln_qkv_kernel<<<nrow / 4, 256, 0, stream>>>(log_ids, item_emb,
                                                ln1_g, ln1_b,
                                                wt + 0 * DD * DD, bq,
                                                wt + 1 * DD * DD, bk,
                                                wt + 2 * DD * DD, bv,
                                                posK, posV,
                                                q, Qb, Kb, Vb);
    attn_kernel<<<BB * 25, 512, 0, stream>>>(Qb, Kb, Vb, log_times, tKT, tV_emb, att);

    // layer 0 tail + layer 1 entry
    mid_kernel<<<nrow / 4, 256, 0, stream>>>(q, att,
                                             ln2_g, ln2_b,
                                             W1T0, b1, W2T0, b2,
                                             log_ids,
                                             ln1_g + DD, ln1_b + DD,
                                             wt + 5 * DD * DD, bq + DD,
                                             wt + 6 * DD * DD, bk + DD,
                                             wt + 7 * DD * DD, bv + DD,
                                             posK, posV,
                                             q, Qb, Kb, Vb);
    attn_kernel<<<BB * 25, 512, 0, stream>>>(Qb, Kb, Vb, log_times, tKT, tV_emb, att);

    // layer 1 tail + final logits
    end_kernel<<<nrow / 4, 256, 0, stream>>>(q, att,
                                             ln2_g + DD, ln2_b + DD,
                                             W1T1, b1 + DD, W2T1, b2 + DD,
                                             log_ids,
                                             lnf_g, lnf_b, item_emb,
                                             pos_ids, neg_ids, (float*)d_out);
}

// Round 10
// 183.344 us; speedup vs baseline: 1.1484x; 1.1484x over previous
//
#include <hip/hip_runtime.h>
#include <math.h>

// TiSASRec forward on MI355X — round 9:
//  - attn: exact R4 structure (best measured, 47.7us): qt_s LDS stage,
//    balanced {i,99-i,100+i,199-i} blocks, 4-key score groups, per-wave
//    softmax, 4-acc PV.
//  - qt table computation fused into ln_qkv/mid (producer blocks compute
//    their own 4 rows' Qt slice) -> qt_kernel launches removed (8->6).
// B=32, L=200, D=64, H=2, dh=32, NL=2.
#define BB 32
#define LLEN 200
#define DD 64
#define HH 2
#define NLAYER 2
#define BLD (BB * LLEN * DD)
#define TSPAN1 366   // TIME_SPAN+1

__device__ inline float waveSum(float v) {
#pragma unroll
    for (int off = 32; off > 0; off >>= 1) v += __shfl_xor(v, off);
    return v;
}
__device__ inline float halfSum(float v) {
    v += __shfl_xor(v, 1);
    v += __shfl_xor(v, 2);
    v += __shfl_xor(v, 4);
    v += __shfl_xor(v, 8);
    v += __shfl_xor(v, 16);
    return v;
}
__device__ inline float halfMax(float v) {
    v = fmaxf(v, __shfl_xor(v, 1));
    v = fmaxf(v, __shfl_xor(v, 2));
    v = fmaxf(v, __shfl_xor(v, 4));
    v = fmaxf(v, __shfl_xor(v, 8));
    v = fmaxf(v, __shfl_xor(v, 16));
    return v;
}

// qt tail: block computed Qsh[4][64] for rows base..base+3; each thread owns
// t values (t = tid, tid+256); Qt[row][h*366+t] = sum_{d in h} Qsh[r][d]*tKT[d][t]
__device__ inline void qt_tail(const float (*Qsh)[DD], const float* __restrict__ tKT,
                               float* __restrict__ Qt_g, int base) {
    int tid = threadIdx.x;
    for (int t = tid; t < TSPAN1; t += 256) {
        const float* tk = tKT + t;
        float a0 = 0, a1 = 0, a2 = 0, a3 = 0;
#pragma unroll 8
        for (int d = 0; d < 32; ++d) {
            float v = tk[d * TSPAN1];
            a0 = fmaf(v, Qsh[0][d], a0);
            a1 = fmaf(v, Qsh[1][d], a1);
            a2 = fmaf(v, Qsh[2][d], a2);
            a3 = fmaf(v, Qsh[3][d], a3);
        }
        Qt_g[(base + 0) * (2 * TSPAN1) + t] = a0;
        Qt_g[(base + 1) * (2 * TSPAN1) + t] = a1;
        Qt_g[(base + 2) * (2 * TSPAN1) + t] = a2;
        Qt_g[(base + 3) * (2 * TSPAN1) + t] = a3;
        float b0 = 0, b1 = 0, b2 = 0, b3 = 0;
#pragma unroll 8
        for (int d = 32; d < 64; ++d) {
            float v = tk[d * TSPAN1];
            b0 = fmaf(v, Qsh[0][d], b0);
            b1 = fmaf(v, Qsh[1][d], b1);
            b2 = fmaf(v, Qsh[2][d], b2);
            b3 = fmaf(v, Qsh[3][d], b3);
        }
        Qt_g[(base + 0) * (2 * TSPAN1) + TSPAN1 + t] = b0;
        Qt_g[(base + 1) * (2 * TSPAN1) + TSPAN1 + t] = b1;
        Qt_g[(base + 2) * (2 * TSPAN1) + TSPAN1 + t] = b2;
        Qt_g[(base + 3) * (2 * TSPAN1) + TSPAN1 + t] = b3;
    }
}

// grid=11: m<10 -> transpose 64x64 weights; m==10 -> tK_emb^T [64][366]
__global__ void transpose_kernel(const float* __restrict__ Wq,
                                 const float* __restrict__ Wk,
                                 const float* __restrict__ Wv,
                                 const float* __restrict__ W1,
                                 const float* __restrict__ W2,
                                 const float* __restrict__ tK_emb,
                                 float* __restrict__ wt,
                                 float* __restrict__ tKT) {
    int m = blockIdx.x;
    if (m < 10) {
        const float* src;
        switch (m % 5) {
            case 0: src = Wq; break;
            case 1: src = Wk; break;
            case 2: src = Wv; break;
            case 3: src = W1; break;
            default: src = W2; break;
        }
        src += (m / 5) * DD * DD;
        float* dst = wt + m * DD * DD;
        for (int e = threadIdx.x; e < DD * DD; e += 256) {
            int d = e >> 6, j = e & 63;
            dst[j * DD + d] = src[e];
        }
    } else {
        for (int e = threadIdx.x; e < TSPAN1 * DD; e += 256) {
            int t = e >> 6, d = e & 63;
            tKT[d * TSPAN1 + t] = tK_emb[e];
        }
    }
}

// Layer-0 entry + fused qt: 4 rows/block, wave per row. Embedding gather
// fused. q=LN(x); Q=q@WqT+bq; K,V likewise + pos fold; then qt tail.
__global__ void ln_qkv_kernel(const int* __restrict__ log_ids,
                              const float* __restrict__ item_emb,
                              const float* __restrict__ g,
                              const float* __restrict__ bln,
                              const float* __restrict__ WqT, const float* __restrict__ bq,
                              const float* __restrict__ WkT, const float* __restrict__ bk,
                              const float* __restrict__ WvT, const float* __restrict__ bv,
                              const float* __restrict__ posK,
                              const float* __restrict__ posV,
                              const float* __restrict__ tKT,
                              float* __restrict__ q,
                              float* __restrict__ Q, float* __restrict__ K,
                              float* __restrict__ V,
                              float* __restrict__ Qt_g) {
    __shared__ float qs[4][DD], xs[4][DD], Qsh[4][DD];
    int tid = threadIdx.x;
    int wid = tid >> 6, d = tid & 63;
    int row = blockIdx.x * 4 + wid;
    int l = row % LLEN;
    int id = log_ids[row];
    float xv = (id == 0) ? 0.0f : item_emb[id * DD + d] * 8.0f;  // sqrt(64)*keep
    xs[wid][d] = xv;
    float m = waveSum(xv) * (1.0f / 64.0f);
    float c = xv - m;
    float var = waveSum(c * c) * (1.0f / 64.0f);
    float qv = (c / sqrtf(var + 1e-8f)) * g[d] + bln[d];
    qs[wid][d] = qv;
    q[row * DD + d] = qv;
    float aq = bq[d], ak = bk[d], av = bv[d];
#pragma unroll 8
    for (int j = 0; j < DD; ++j) {
        aq = fmaf(qs[wid][j], WqT[j * DD + d], aq);
        ak = fmaf(xs[wid][j], WkT[j * DD + d], ak);
        av = fmaf(xs[wid][j], WvT[j * DD + d], av);
    }
    Q[row * DD + d] = aq;
    K[row * DD + d] = ak + posK[l * DD + d];
    V[row * DD + d] = av + posV[l * DD + d];
    Qsh[wid][d] = aq;
    __syncthreads();
    qt_tail(Qsh, tKT, Qt_g, blockIdx.x * 4);
}

// Attention: exact R4 structure. wave-per-query {i,99-i,100+i,199-i};
// per-wave phases; qt_s staged from global Qt; 4-key score groups.
__global__ void attn_kernel(const float* __restrict__ Q,
                            const float* __restrict__ Keff,
                            const float* __restrict__ Veff,
                            const int* __restrict__ log_times,
                            const float* __restrict__ Qt_g,
                            const float* __restrict__ tV_emb,
                            float* __restrict__ out) {
    __shared__ int t_s[LLEN];
    __shared__ float sc[4][HH][LLEN];
    __shared__ unsigned short tm_s[4][LLEN];
    __shared__ float qt_s[4][2 * TSPAN1];

    int tid = threadIdx.x;
    int wid = tid >> 6;
    int lane = tid & 63;
    int bi = blockIdx.x / 50;
    int i = blockIdx.x % 50;
    int qi = (wid == 0) ? i : (wid == 1) ? (99 - i) : (wid == 2) ? (100 + i) : (199 - i);
    int row = bi * LLEN + qi;
    int len = qi + 1;

    if (tid < LLEN) t_s[tid] = log_times[bi * LLEN + tid];
    __syncthreads();

    // stage this query's Qt row (732 floats) into LDS
    const float* qtrow_g = Qt_g + row * (2 * TSPAN1);
    for (int e = lane; e < 2 * TSPAN1; e += 64) qt_s[wid][e] = qtrow_g[e];

    // bucket table for this query
    int tq = t_s[qi];
    for (int k = lane; k < len; k += 64) {
        int dt = tq - t_s[k];
        if (dt < 0) dt = -dt;
        float dtf = fminf((float)dt * (1.0f / 86400.0f), 365.0f);
        tm_s[wid][k] = (unsigned short)(int)dtf;
    }

    int h = lane >> 5;       // head
    int l5 = lane & 31;
    int cch = l5 >> 2;       // channel chunk 0..7
    int jo = l5 & 3;         // key offset in group
    float4 qv = ((const float4*)(Q + row * DD))[h * 8 + cch];
    const float4* K4 = (const float4*)(Keff + bi * LLEN * DD);
    const float scale = 0.17677669529663687f;  // 1/sqrt(32)

    // phase 1: scores, 4 keys per iteration
    for (int k0 = 0; k0 < len; k0 += 4) {
        int k = k0 + jo;
        int kc = (k < len) ? k : (len - 1);
        int bucket = tm_s[wid][kc];
        float4 kv = K4[kc * 16 + h * 8 + cch];
        float p = qv.x * kv.x + qv.y * kv.y + qv.z * kv.z + qv.w * kv.w;
        p += __shfl_xor(p, 4);
        p += __shfl_xor(p, 8);
        p += __shfl_xor(p, 16);   // full 32-dot for (h, key k)
        float s = (p + qt_s[wid][h * TSPAN1 + bucket]) * scale;
        if (cch == 0 && k < len) sc[wid][h][k] = s;
    }

    // phase 2: softmax (lanes 0..31 head 0, 32..63 head 1; same wave)
    {
        float m = -INFINITY;
        for (int k = l5; k < len; k += 32) m = fmaxf(m, sc[wid][h][k]);
        m = halfMax(m);
        float s = 0.0f;
        for (int k = l5; k < len; k += 32) {
            float e = expf(sc[wid][h][k] - m);
            sc[wid][h][k] = e;
            s += e;
        }
        s = halfSum(s);
        float inv = 1.0f / s;
        for (int k = l5; k < len; k += 32) sc[wid][h][k] *= inv;
    }

    // phase 3: out[d] = sum_k A[h][k] * (V_eff[k][d] + tV[bucket[k]][d])
    const float* Vb = Veff + bi * LLEN * DD + lane;
    const float* tVl = tV_emb + lane;
    float acc0 = 0.0f, acc1 = 0.0f, acc2 = 0.0f, acc3 = 0.0f;
    int k = 0;
    for (; k + 4 <= len; k += 4) {
        int b0 = tm_s[wid][k + 0];
        int b1 = tm_s[wid][k + 1];
        int b2 = tm_s[wid][k + 2];
        int b3 = tm_s[wid][k + 3];
        float a0 = sc[wid][h][k + 0];
        float a1 = sc[wid][h][k + 1];
        float a2 = sc[wid][h][k + 2];
        float a3 = sc[wid][h][k + 3];
        acc0 = fmaf(a0, Vb[(k + 0) * DD] + tVl[b0 * DD], acc0);
        acc1 = fmaf(a1, Vb[(k + 1) * DD] + tVl[b1 * DD], acc1);
        acc2 = fmaf(a2, Vb[(k + 2) * DD] + tVl[b2 * DD], acc2);
        acc3 = fmaf(a3, Vb[(k + 3) * DD] + tVl[b3 * DD], acc3);
    }
    for (; k < len; ++k) {
        int b0 = tm_s[wid][k];
        acc0 = fmaf(sc[wid][h][k], Vb[k * DD] + tVl[b0 * DD], acc0);
    }
    out[row * DD + lane] = (acc0 + acc1) + (acc2 + acc3);
}

// MID + fused qt: addln_ffn(layer i) + ln_qkv(layer i+1) + qt tail.
__global__ void mid_kernel(const float* __restrict__ qin,
                           const float* __restrict__ att,
                           const float* __restrict__ g2, const float* __restrict__ b2ln,
                           const float* __restrict__ W1T, const float* __restrict__ b1v,
                           const float* __restrict__ W2T, const float* __restrict__ b2v,
                           const int* __restrict__ log_ids,
                           const float* __restrict__ g1n, const float* __restrict__ b1n,
                           const float* __restrict__ WqT, const float* __restrict__ bq,
                           const float* __restrict__ WkT, const float* __restrict__ bk,
                           const float* __restrict__ WvT, const float* __restrict__ bv,
                           const float* __restrict__ posK,
                           const float* __restrict__ posV,
                           const float* __restrict__ tKT,
                           float* __restrict__ q,
                           float* __restrict__ Q, float* __restrict__ K,
                           float* __restrict__ V,
                           float* __restrict__ Qt_g) {
    __shared__ float xs[4][DD], hs[4][DD], qs[4][DD], Qsh[4][DD];
    int tid = threadIdx.x;
    int wid = tid >> 6, d = tid & 63;
    int row = blockIdx.x * 4 + wid;
    int l = row % LLEN;
    // --- addln + FFN ---
    float v = qin[row * DD + d] + att[row * DD + d];
    float m = waveSum(v) * (1.0f / 64.0f);
    float c = v - m;
    float var = waveSum(c * c) * (1.0f / 64.0f);
    float xv = (c / sqrtf(var + 1e-8f)) * g2[d] + b2ln[d];
    xs[wid][d] = xv;
    float a = b1v[d];
#pragma unroll 8
    for (int j = 0; j < DD; ++j) a = fmaf(xs[wid][j], W1T[j * DD + d], a);
    hs[wid][d] = fmaxf(a, 0.0f);
    float o = b2v[d];
#pragma unroll 8
    for (int j = 0; j < DD; ++j) o = fmaf(hs[wid][j], W2T[j * DD + d], o);
    float res = xv + o;
    if (log_ids[row] == 0) res = 0.0f;
    // --- next layer: LN1 + QKV projection ---
    float m2 = waveSum(res) * (1.0f / 64.0f);
    float c2 = res - m2;
    float var2 = waveSum(c2 * c2) * (1.0f / 64.0f);
    float qv = (c2 / sqrtf(var2 + 1e-8f)) * g1n[d] + b1n[d];
    qs[wid][d] = qv;
    xs[wid][d] = res;
    q[row * DD + d] = qv;
    float aq = bq[d], ak = bk[d], av = bv[d];
#pragma unroll 8
    for (int j = 0; j < DD; ++j) {
        aq = fmaf(qs[wid][j], WqT[j * DD + d], aq);
        ak = fmaf(xs[wid][j], WkT[j * DD + d], ak);
        av = fmaf(xs[wid][j], WvT[j * DD + d], av);
    }
    Q[row * DD + d] = aq;
    K[row * DD + d] = ak + posK[l * DD + d];
    V[row * DD + d] = av + posV[l * DD + d];
    Qsh[wid][d] = aq;
    __syncthreads();
    qt_tail(Qsh, tKT, Qt_g, blockIdx.x * 4);
}

// END: addln_ffn(last layer) fused with final LN + logits. 4 rows/block.
__global__ void end_kernel(const float* __restrict__ qin,
                           const float* __restrict__ att,
                           const float* __restrict__ g2, const float* __restrict__ b2ln,
                           const float* __restrict__ W1T, const float* __restrict__ b1v,
                           const float* __restrict__ W2T, const float* __restrict__ b2v,
                           const int* __restrict__ log_ids,
                           const float* __restrict__ lnf_g, const float* __restrict__ lnf_b,
                           const float* __restrict__ item_emb,
                           const int* __restrict__ pos_ids,
                           const int* __restrict__ neg_ids,
                           float* __restrict__ out) {
    __shared__ float xs[4][DD], hs[4][DD];
    int tid = threadIdx.x;
    int wid = tid >> 6, d = tid & 63;
    int row = blockIdx.x * 4 + wid;
    float v = qin[row * DD + d] + att[row * DD + d];
    float m = waveSum(v) * (1.0f / 64.0f);
    float c = v - m;
    float var = waveSum(c * c) * (1.0f / 64.0f);
    float xv = (c / sqrtf(var + 1e-8f)) * g2[d] + b2ln[d];
    xs[wid][d] = xv;
    float a = b1v[d];
#pragma unroll 8
    for (int j = 0; j < DD; ++j) a = fmaf(xs[wid][j], W1T[j * DD + d], a);
    hs[wid][d] = fmaxf(a, 0.0f);
    float o = b2v[d];
#pragma unroll 8
    for (int j = 0; j < DD; ++j) o = fmaf(hs[wid][j], W2T[j * DD + d], o);
    float res = xv + o;
    if (log_ids[row] == 0) res = 0.0f;
    // --- final LN + logits ---
    float m2 = waveSum(res) * (1.0f / 64.0f);
    float c2 = res - m2;
    float var2 = waveSum(c2 * c2) * (1.0f / 64.0f);
    float f = (c2 / sqrtf(var2 + 1e-8f)) * lnf_g[d] + lnf_b[d];
    int pid = pos_ids[row];
    int nid = neg_ids[row];
    float p = waveSum(f * item_emb[pid * DD + d]);
    float n = waveSum(f * item_emb[nid * DD + d]);
    if (d == 0) {
        out[row] = p;
        out[BB * LLEN + row] = n;
    }
}

extern "C" void kernel_launch(void* const* d_in, const int* in_sizes, int n_in,
                              void* d_out, int out_size, void* d_ws, size_t ws_size,
                              hipStream_t stream) {
    const int* log_ids = (const int*)d_in[0];
    const int* log_times = (const int*)d_in[1];
    const int* pos_ids = (const int*)d_in[2];
    const int* neg_ids = (const int*)d_in[3];
    const float* item_emb = (const float*)d_in[4];
    const float* posK = (const float*)d_in[5];
    const float* posV = (const float*)d_in[6];
    const float* tK_emb = (const float*)d_in[7];
    const float* tV_emb = (const float*)d_in[8];
    const float* ln1_g = (const float*)d_in[9];
    const float* ln1_b = (const float*)d_in[10];
    const float* Wq = (const float*)d_in[11];
    const float* bq = (const float*)d_in[12];
    const float* Wk = (const float*)d_in[13];
    const float* bk = (const float*)d_in[14];
    const float* Wv = (const float*)d_in[15];
    const float* bv = (const float*)d_in[16];
    const float* ln2_g = (const float*)d_in[17];
    const float* ln2_b = (const float*)d_in[18];
    const float* W1 = (const float*)d_in[19];
    const float* b1 = (const float*)d_in[20];
    const float* W2 = (const float*)d_in[21];
    const float* b2 = (const float*)d_in[22];
    const float* lnf_g = (const float*)d_in[23];
    const float* lnf_b = (const float*)d_in[24];

    float* ws = (float*)d_ws;
    float* q = ws;                        // ln1 output (residual)
    float* Qb = q + BLD;
    float* Kb = Qb + BLD;
    float* Vb = Kb + BLD;
    float* att = Vb + BLD;
    float* wt = att + BLD;                // 10 x 64x64 transposed weights
    float* tKT = wt + 10 * DD * DD;       // [64][366]
    float* Qt = tKT + DD * TSPAN1;        // [6400][732]

    const int nrow = BB * LLEN;           // 6400

    const float* W1T0 = wt + 3 * DD * DD;
    const float* W2T0 = wt + 4 * DD * DD;
    const float* W1T1 = wt + 8 * DD * DD;
    const float* W2T1 = wt + 9 * DD * DD;

    transpose_kernel<<<11, 256, 0, stream>>>(Wq, Wk, Wv, W1, W2, tK_emb, wt, tKT);

    // layer 0 entry (embed + qt fused)
    ln_qkv_kernel<<<nrow / 4, 256, 0, stream>>>(log_ids, item_emb,
                                                ln1_g, ln1_b,
                                                wt + 0 * DD * DD, bq,
                                                wt + 1 * DD * DD, bk,
                                                wt + 2 * DD * DD, bv,
                                                posK, posV, tKT,
                                                q, Qb, Kb, Vb, Qt);
    attn_kernel<<<BB * 50, 256, 0, stream>>>(Qb, Kb, Vb, log_times, Qt, tV_emb, att);

    // layer 0 tail + layer 1 entry (+ qt fused)
    mid_kernel<<<nrow / 4, 256, 0, stream>>>(q, att,
                                             ln2_g, ln2_b,
                                             W1T0, b1, W2T0, b2,
                                             log_ids,
                                             ln1_g + DD, ln1_b + DD,
                                             wt + 5 * DD * DD, bq + DD,
                                             wt + 6 * DD * DD, bk + DD,
                                             wt + 7 * DD * DD, bv + DD,
                                             posK, posV, tKT,
                                             q, Qb, Kb, Vb, Qt);
    attn_kernel<<<BB * 50, 256, 0, stream>>>(Qb, Kb, Vb, log_times, Qt, tV_emb, att);

    // layer 1 tail + final logits
    end_kernel<<<nrow / 4, 256, 0, stream>>>(q, att,
                                             ln2_g + DD, ln2_b + DD,
                                             W1T1, b1 + DD, W2T1, b2 + DD,
                                             log_ids,
                                             lnf_g, lnf_b, item_emb,
                                             pos_ids, neg_ids, (float*)d_out);
}